// Round 8
// baseline (2743.375 us; speedup 1.0000x reference)
//
#include <hip/hip_runtime.h>
#include <float.h>

// ---------------------------------------------------------------------------
// VALU-f64 GEMM v2: C[M,N] = op(A[M,K]) @ W[K,N] + bias (f32 store, f64 math).
// op = identity or (FUSE) per-K-column BN+ReLU in f64.
// Tile 128(M) x 64(N), BK=16, 256 threads, 8x4 f64 micro-tile per thread.
// Round-4-identical compute order (green, absmax 0.0078); adds T14
// async-STAGE split: next tile's global loads issued before compute so
// HBM latency hides under the 16-k f64 FMA phase. 24 KB LDS.
// ---------------------------------------------------------------------------
template<bool FUSE>
__global__ __launch_bounds__(256)
void gemm_f64(const float* __restrict__ A, const float* __restrict__ W,
              const float* __restrict__ bias,
              const double* __restrict__ scl, const double* __restrict__ shf,
              float* __restrict__ C, int M, int N, int K)
{
    __shared__ double Asd[16][128];   // [k][row] 16 KB
    __shared__ double Bsd[16][64];    // [k][col]  8 KB
    const int tid = threadIdx.x;
    const int tx = tid & 15;
    const int ty = tid >> 4;
    const int rowBase = blockIdx.y << 7;
    const int colBase = blockIdx.x << 6;

    const float* Ab = A + (size_t)rowBase * K;
    const float* Wb = W + colBase;

    // loop-invariant staging coordinates
    const int r0  = tid >> 2,         c40 = (tid & 3) << 2;          // A part 0
    const int r1  = (256 + tid) >> 2, c41 = ((256 + tid) & 3) << 2;  // A part 1
    const int kr  = tid >> 4,         ccB = (tid & 15) << 2;         // B
    const float* ApA0 = Ab + (size_t)r0 * K + c40;
    const float* ApA1 = Ab + (size_t)r1 * K + c41;
    const float* ApB  = Wb + (size_t)kr * N + ccB;

    // prologue: prefetch tile k0=0 into registers
    float4 pa0 = *reinterpret_cast<const float4*>(ApA0);
    float4 pa1 = *reinterpret_cast<const float4*>(ApA1);
    float4 pb  = *reinterpret_cast<const float4*>(ApB);

    double acc[8][4];
    #pragma unroll
    for (int i = 0; i < 8; ++i)
        #pragma unroll
        for (int j = 0; j < 4; ++j) acc[i][j] = 0.0;

    for (int k0 = 0; k0 < K; k0 += 16) {
        // write staged registers -> LDS (f64 convert; BN+ReLU fused for A)
        {
            double d0 = (double)pa0.x, d1 = (double)pa0.y,
                   d2 = (double)pa0.z, d3 = (double)pa0.w;
            if (FUSE) {
                int kk = k0 + c40;
                d0 = fmax(fma(d0, scl[kk+0], shf[kk+0]), 0.0);
                d1 = fmax(fma(d1, scl[kk+1], shf[kk+1]), 0.0);
                d2 = fmax(fma(d2, scl[kk+2], shf[kk+2]), 0.0);
                d3 = fmax(fma(d3, scl[kk+3], shf[kk+3]), 0.0);
            }
            Asd[c40+0][r0] = d0; Asd[c40+1][r0] = d1;
            Asd[c40+2][r0] = d2; Asd[c40+3][r0] = d3;

            double e0 = (double)pa1.x, e1 = (double)pa1.y,
                   e2 = (double)pa1.z, e3 = (double)pa1.w;
            if (FUSE) {
                int kk = k0 + c41;
                e0 = fmax(fma(e0, scl[kk+0], shf[kk+0]), 0.0);
                e1 = fmax(fma(e1, scl[kk+1], shf[kk+1]), 0.0);
                e2 = fmax(fma(e2, scl[kk+2], shf[kk+2]), 0.0);
                e3 = fmax(fma(e3, scl[kk+3], shf[kk+3]), 0.0);
            }
            Asd[c41+0][r1] = e0; Asd[c41+1][r1] = e1;
            Asd[c41+2][r1] = e2; Asd[c41+3][r1] = e3;

            Bsd[kr][ccB+0] = (double)pb.x; Bsd[kr][ccB+1] = (double)pb.y;
            Bsd[kr][ccB+2] = (double)pb.z; Bsd[kr][ccB+3] = (double)pb.w;
        }
        __syncthreads();                 // LDS tile ready

        // issue next tile's loads NOW -> latency hides under compute
        if (k0 + 16 < K) {
            pa0 = *reinterpret_cast<const float4*>(ApA0 + (k0 + 16));
            pa1 = *reinterpret_cast<const float4*>(ApA1 + (k0 + 16));
            pb  = *reinterpret_cast<const float4*>(ApB + (size_t)(k0 + 16) * N);
        }

        #pragma unroll
        for (int k = 0; k < 16; ++k) {
            double a[8], b[4];
            #pragma unroll
            for (int i = 0; i < 8; ++i) a[i] = Asd[k][(ty << 3) + i];
            #pragma unroll
            for (int j = 0; j < 4; ++j) b[j] = Bsd[k][(tx << 2) + j];
            #pragma unroll
            for (int i = 0; i < 8; ++i)
                #pragma unroll
                for (int j = 0; j < 4; ++j)
                    acc[i][j] = fma(a[i], b[j], acc[i][j]);
        }
        __syncthreads();                 // compute done; LDS reusable
    }

    double bv[4];
    #pragma unroll
    for (int j = 0; j < 4; ++j) bv[j] = (double)bias[colBase + (tx << 2) + j];
    #pragma unroll
    for (int i = 0; i < 8; ++i) {
        size_t row = (size_t)rowBase + (ty << 3) + i;
        float* cp = C + row * N + colBase + (tx << 2);
        #pragma unroll
        for (int j = 0; j < 4; ++j) cp[j] = (float)(acc[i][j] + bv[j]);
    }
}

// ---------------------------------------------------------------------------
// Column stats (f64, deterministic two-stage, no atomics).
// ---------------------------------------------------------------------------
__global__ __launch_bounds__(256)
void colstats_f64(const float* __restrict__ C, double* __restrict__ ps,
                  double* __restrict__ ps2, int N, int rowsPer)
{
    int col = blockIdx.x * 256 + threadIdx.x;
    const float* p = C + (size_t)blockIdx.y * rowsPer * N + col;
    double s = 0.0, s2 = 0.0;
    for (int r = 0; r < rowsPer; ++r) {
        double v = (double)p[(size_t)r * N];
        s += v;
        s2 = fma(v, v, s2);
    }
    ps [blockIdx.y * N + col] = s;
    ps2[blockIdx.y * N + col] = s2;
}

__global__ __launch_bounds__(256)
void bn_finalize_f64(const double* __restrict__ ps, const double* __restrict__ ps2,
                     const float* __restrict__ gamma, const float* __restrict__ beta,
                     double* __restrict__ scl, double* __restrict__ shf,
                     int N, int chunks, double invM)
{
    int col = blockIdx.x * 256 + threadIdx.x;
    if (col >= N) return;
    double s = 0.0, s2 = 0.0;
    for (int c = 0; c < chunks; ++c) { s += ps[c * N + col]; s2 += ps2[c * N + col]; }
    double mean = s * invM;
    double var  = fma(s2, invM, -mean * mean);
    double sc = (double)gamma[col] / sqrt(var + 1e-5);
    scl[col] = sc;
    shf[col] = fma(-mean, sc, (double)beta[col]);
}

// ||c_j||^2 per codebook row, f64
__global__ __launch_bounds__(256)
void cnorm_f64(const float* __restrict__ cb, double* __restrict__ cn)
{
    int j = blockIdx.x * 256 + threadIdx.x;   // 0..1023
    const float* p = cb + (size_t)j * 128;
    double s = 0.0;
    #pragma unroll 4
    for (int d = 0; d < 128; ++d) { double v = (double)p[d]; s = fma(v, v, s); }
    cn[j] = s;
}

// ---------------------------------------------------------------------------
// VALU-f64 VQ v2: per block 64 z-rows (BN2 in f64 on load, Zsd [dim][row]
// f64 LDS-resident 64 KB), 1024 codes in chunks of 128; codebook staged as
// f64 Bsd[8][128] (8 KB, converts amortized at stage time) with T14
// register-prefetch of the next tile. Round-4-identical distance math and
// tie-break (first occurrence). LDS 72.3 KB -> 2 blocks/CU.
// ---------------------------------------------------------------------------
__global__ __launch_bounds__(256)
void vq_f64(const float* __restrict__ Z, const double* __restrict__ scl,
            const double* __restrict__ shf, const float* __restrict__ cb,
            const double* __restrict__ cn, float* __restrict__ out)
{
    __shared__ double Zsd[128][64];  // [dim][row] 64 KB
    __shared__ double Bsd[8][128];   // [k][code]   8 KB
    __shared__ int    rowIdx[64];

    const int tid = threadIdx.x;
    const int tx = tid & 15, ty = tid >> 4;
    const size_t zbase = (size_t)blockIdx.x << 13;   // *64*128

    // load + BN2 (f64): flat f32 index -> BN column = ((m&3)<<7)+d
    #pragma unroll
    for (int l = 0; l < 8; ++l) {
        int li = (l << 8) + tid;          // float4 index 0..2047
        int m  = li >> 5;
        int d0 = (li & 31) << 2;
        float4 v = *reinterpret_cast<const float4*>(Z + zbase + ((size_t)li << 2));
        int sb = ((m & 3) << 7) + d0;
        Zsd[d0+0][m] = fma((double)v.x, scl[sb+0], shf[sb+0]);
        Zsd[d0+1][m] = fma((double)v.y, scl[sb+1], shf[sb+1]);
        Zsd[d0+2][m] = fma((double)v.z, scl[sb+2], shf[sb+2]);
        Zsd[d0+3][m] = fma((double)v.w, scl[sb+3], shf[sb+3]);
    }

    // codebook staging coords (loop-invariant): thread -> (code, 4-dim slab)
    const int codeS = tid >> 1;
    const int kbS   = (tid & 1) << 2;
    const float* cbS = cb + ((size_t)codeS << 7) + kbS;

    // prologue prefetch: (cc=0, k0=0)
    float4 pbv = *reinterpret_cast<const float4*>(cbS);

    double bestV[4]; int bestI[4];
    #pragma unroll
    for (int i = 0; i < 4; ++i) { bestV[i] = DBL_MAX; bestI[i] = 0x7fffffff; }

    for (int cc = 0; cc < 1024; cc += 128) {
        double acc[4][8];
        #pragma unroll
        for (int i = 0; i < 4; ++i)
            #pragma unroll
            for (int j = 0; j < 8; ++j) acc[i][j] = 0.0;

        for (int k0 = 0; k0 < 128; k0 += 8) {
            __syncthreads();   // prev compute done (first iter: Zsd visible)
            Bsd[kbS+0][codeS] = (double)pbv.x;
            Bsd[kbS+1][codeS] = (double)pbv.y;
            Bsd[kbS+2][codeS] = (double)pbv.z;
            Bsd[kbS+3][codeS] = (double)pbv.w;
            __syncthreads();   // Bsd ready

            // prefetch next stage tile -> flies under the 8-k compute
            {
                int nk = k0 + 8, ncc = cc;
                if (nk == 128) { nk = 0; ncc = cc + 128; }
                if (ncc < 1024)
                    pbv = *reinterpret_cast<const float4*>(
                        cbS + (((size_t)ncc << 7) + nk));
            }

            #pragma unroll
            for (int k = 0; k < 8; ++k) {
                double a[4], b[8];
                #pragma unroll
                for (int i = 0; i < 4; ++i) a[i] = Zsd[k0+k][(ty << 2) + i];
                #pragma unroll
                for (int j = 0; j < 4; ++j) {
                    b[j]   = Bsd[k][(tx << 2) + j];
                    b[4+j] = Bsd[k][64 + (tx << 2) + j];
                }
                #pragma unroll
                for (int i = 0; i < 4; ++i)
                    #pragma unroll
                    for (int j = 0; j < 8; ++j)
                        acc[i][j] = fma(a[i], b[j], acc[i][j]);
            }
        }
        // scores + running argmin (codes ascend within thread -> first occurrence)
        #pragma unroll
        for (int i = 0; i < 4; ++i) {
            #pragma unroll
            for (int j = 0; j < 8; ++j) {
                int code = cc + ((j < 4) ? ((tx << 2) + j) : (64 + (tx << 2) + (j - 4)));
                double d = fma(-2.0, acc[i][j], cn[code]);
                if (d < bestV[i] || (d == bestV[i] && code < bestI[i])) {
                    bestV[i] = d; bestI[i] = code;
                }
            }
        }
    }

    // cross-tx (lane bits 0..3) min-reduce with lowest-index tie-break
    #pragma unroll
    for (int i = 0; i < 4; ++i) {
        double v = bestV[i]; int idx = bestI[i];
        #pragma unroll
        for (int m = 1; m <= 8; m <<= 1) {
            double ov = __shfl_xor(v, m, 64);
            int    oi = __shfl_xor(idx, m, 64);
            if (ov < v || (ov == v && oi < idx)) { v = ov; idx = oi; }
        }
        if (tx == 0) rowIdx[(ty << 2) + i] = idx;
    }
    __syncthreads();

    // gather codebook rows -> out (overwrites the region this block read)
    #pragma unroll
    for (int l = 0; l < 8; ++l) {
        int li = (l << 8) + tid;
        int m  = li >> 5;
        int d0 = (li & 31) << 2;
        float4 v = *reinterpret_cast<const float4*>(cb + ((size_t)rowIdx[m] << 7) + d0);
        *reinterpret_cast<float4*>(out + zbase + ((size_t)li << 2)) = v;
    }
}

// ---------------------------------------------------------------------------
extern "C" void kernel_launch(void* const* d_in, const int* in_sizes, int n_in,
                              void* d_out, int out_size, void* d_ws, size_t ws_size,
                              hipStream_t stream)
{
    const float* x      = (const float*)d_in[0];
    const float* ew1    = (const float*)d_in[1];
    const float* eb1    = (const float*)d_in[2];
    const float* eg1    = (const float*)d_in[3];
    const float* ebt1   = (const float*)d_in[4];
    const float* ew2    = (const float*)d_in[5];
    const float* eb2    = (const float*)d_in[6];
    const float* eg2    = (const float*)d_in[7];
    const float* ebt2   = (const float*)d_in[8];
    const float* cb     = (const float*)d_in[9];
    float* out = (float*)d_out;

    constexpr int M  = 32768;
    constexpr int K1 = 512;
    constexpr int N1 = 1024;   // H_enc
    constexpr int N2 = 512;    // Cout
    constexpr int CHUNKS = 64;

    // workspace carve. C1 f32 (128 MB, 8B-aligned boundary), then f64 scratch.
    float*  C1   = (float*)d_ws;                      // M*N1 floats
    double* psd  = (double*)(C1 + (size_t)M * N1);    // 64*1024
    double* ps2d = psd  + (size_t)CHUNKS * N1;        // 64*1024
    double* scl1 = ps2d + (size_t)CHUNKS * N1;        // 1024
    double* shf1 = scl1 + N1;
    double* scl2 = shf1 + N1;                         // 512
    double* shf2 = scl2 + N2;
    double* cnd  = shf2 + N2;                         // 1024
    float*  C2   = out;                               // VQ reads region into LDS before overwrite

    // 1) C1 = x @ w1 + b1  (f64 accumulate, prefetched staging)
    gemm_f64<false><<<dim3(N1/64, M/128), 256, 0, stream>>>(
        x, ew1, eb1, nullptr, nullptr, C1, M, N1, K1);
    // 2) BN1 stats (f64)
    colstats_f64<<<dim3(N1/256, CHUNKS), 256, 0, stream>>>(C1, psd, ps2d, N1, M/CHUNKS);
    bn_finalize_f64<<<dim3(N1/256), 256, 0, stream>>>(psd, ps2d, eg1, ebt1, scl1, shf1,
                                                      N1, CHUNKS, 1.0/M);
    // 3) C2 = relu(BN1(C1)) @ w2 + b2  (BN+ReLU fused in f64)
    gemm_f64<true><<<dim3(N2/64, M/128), 256, 0, stream>>>(
        C1, ew2, eb2, scl1, shf1, C2, M, N2, N1);
    // 4) BN2 stats (f64)
    colstats_f64<<<dim3(N2/256, CHUNKS), 256, 0, stream>>>(C2, psd, ps2d, N2, M/CHUNKS);
    bn_finalize_f64<<<dim3(N2/256), 256, 0, stream>>>(psd, ps2d, eg2, ebt2, scl2, shf2,
                                                      N2, CHUNKS, 1.0/M);
    // 5) VQ (f64 distances, f64-staged codebook, prefetched)
    cnorm_f64<<<dim3(4), 256, 0, stream>>>(cb, cnd);
    vq_f64<<<dim3(M*4/64), 256, 0, stream>>>(C2, scl2, shf2, cb, cnd, out);
}